// Round 2
// baseline (903.592 us; speedup 1.0000x reference)
//
#include <hip/hip_runtime.h>
#include <hip/hip_bf16.h>

// 2-layer GCN, N=100000 nodes, E=3.2M edges, dims 128 -> 64 -> 2, fp32.
// Strategy: build dst-CSR per call (no fp32 scatter atomics), gather-side
// aggregation with wave-per-node (lane = feature dim), fused bias+ReLU+W2.
// NOTE: harness passes ALL integer inputs as int32 (edge_index included).

#define DIN  128
#define DHID 64

// ---------------- K1: init deg=1 (self-loop), cnt=0 ----------------
__global__ void k_init(float* deg, int* cnt, int N) {
    int i = blockIdx.x * 256 + threadIdx.x;
    if (i < N) { deg[i] = 1.0f; cnt[i] = 0; }
}

// ---------------- K2: edge histogram: deg += ew, cnt += 1 ----------
__global__ void k_count(const int* __restrict__ ei, const float* __restrict__ ew,
                        float* deg, int* cnt, int E) {
    int e = blockIdx.x * 256 + threadIdx.x;
    if (e < E) {
        int d = ei[E + e];
        atomicAdd(&deg[d], ew[e]);
        atomicAdd(&cnt[d], 1);
    }
}

// ---------------- K3: dinv = rsqrt(deg) in place -------------------
__global__ void k_rsqrt(float* deg, int N) {
    int i = blockIdx.x * 256 + threadIdx.x;
    if (i < N) deg[i] = rsqrtf(deg[i]);  // deg >= 1 always (self-loop)
}

// ---------------- K4: per-block partial sums of cnt ----------------
__global__ void k_partial(const int* __restrict__ cnt, int* bsum, int N) {
    __shared__ int sm[256];
    int i = blockIdx.x * 256 + threadIdx.x;
    sm[threadIdx.x] = (i < N) ? cnt[i] : 0;
    __syncthreads();
    for (int off = 128; off > 0; off >>= 1) {
        if (threadIdx.x < off) sm[threadIdx.x] += sm[threadIdx.x + off];
        __syncthreads();
    }
    if (threadIdx.x == 0) bsum[blockIdx.x] = sm[0];
}

// ---------------- K5: exclusive scan of block sums (1 block) -------
__global__ void k_scan_bsum(int* bsum, int NB) {
    __shared__ int sm[1024];
    int t = threadIdx.x;
    int v = (t < NB) ? bsum[t] : 0;
    sm[t] = v;
    __syncthreads();
    for (int off = 1; off < 1024; off <<= 1) {
        int add = (t >= off) ? sm[t - off] : 0;
        __syncthreads();
        sm[t] += add;
        __syncthreads();
    }
    if (t < NB) bsum[t] = sm[t] - v;  // exclusive
}

// ---------------- K6: row_ptr + next from scanned sums -------------
__global__ void k_rowptr(const int* __restrict__ cnt, const int* __restrict__ bsum,
                         int* rp, int* nxt, int N) {
    __shared__ int sm[256];
    int i = blockIdx.x * 256 + threadIdx.x;
    int c = (i < N) ? cnt[i] : 0;
    sm[threadIdx.x] = c;
    __syncthreads();
    for (int off = 1; off < 256; off <<= 1) {
        int add = (threadIdx.x >= off) ? sm[threadIdx.x - off] : 0;
        __syncthreads();
        sm[threadIdx.x] += add;
        __syncthreads();
    }
    int excl = bsum[blockIdx.x] + sm[threadIdx.x] - c;
    if (i < N) {
        rp[i] = excl;
        nxt[i] = excl;
        if (i == N - 1) rp[N] = excl + c;
    }
}

// ---------------- K7: CSR fill (src idx + precomputed norm) --------
__global__ void k_fill(const int* __restrict__ ei, const float* __restrict__ ew,
                       const float* __restrict__ dinv, int* nxt,
                       int* cs, float* cn, int E) {
    int e = blockIdx.x * 256 + threadIdx.x;
    if (e < E) {
        int s = ei[e];
        int d = ei[E + e];
        int pos = atomicAdd(&nxt[d], 1);
        cs[pos] = s;
        cn[pos] = dinv[s] * ew[e] * dinv[d];
    }
}

// ---------------- K8: h1 = x @ W1  (N x 128 @ 128 x 64) ------------
__global__ __launch_bounds__(256) void k_gemm1(const float* __restrict__ x,
                                               const float* __restrict__ W1,
                                               float* __restrict__ h1,
                                               int N, int iters) {
    __shared__ float wlds[DIN * DHID];  // 32 KB
    __shared__ float xs[4][DIN];        // 2 KB
    for (int t = threadIdx.x; t < DIN * DHID; t += 256) wlds[t] = W1[t];
    __syncthreads();
    int g = threadIdx.x >> 6;
    int lane = threadIdx.x & 63;
    for (int it = 0; it < iters; ++it) {
        int r = blockIdx.x * 4 + g + it * gridDim.x * 4;
        if (r < N) {
            xs[g][lane]      = x[r * DIN + lane];
            xs[g][lane + 64] = x[r * DIN + 64 + lane];
        }
        __syncthreads();
        if (r < N) {
            float acc = 0.0f;
#pragma unroll 8
            for (int k = 0; k < DIN; ++k)
                acc = fmaf(xs[g][k], wlds[k * DHID + lane], acc);
            h1[r * DHID + lane] = acc;
        }
        __syncthreads();
    }
}

// ------- K9: fused layer-1 aggregate + bias + ReLU + @W2 -----------
// one wave per node; lane = feature dim (64)
__global__ __launch_bounds__(256) void k_agg1(const float* __restrict__ h1,
                                              const int* __restrict__ rp,
                                              const int* __restrict__ cs,
                                              const float* __restrict__ cn,
                                              const float* __restrict__ dinv,
                                              const float* __restrict__ b1,
                                              const float* __restrict__ W2,
                                              float* __restrict__ h2, int N) {
    int lane = threadIdx.x & 63;
    int wid = (blockIdx.x * 256 + threadIdx.x) >> 6;
    int nw = (gridDim.x * 256) >> 6;
    float bias = b1[lane];
    float w2a = W2[lane * 2];
    float w2b = W2[lane * 2 + 1];
    for (int i = wid; i < N; i += nw) {
        float di = dinv[i];
        float acc = di * di * h1[i * DHID + lane];
        int s0 = rp[i], e0 = rp[i + 1];
        for (int p = s0; p < e0; p += 64) {
            int idx = p + lane;
            bool v = idx < e0;
            int sN = v ? cs[idx] : 0;
            float wN = v ? cn[idx] : 0.0f;
            int cnt = min(64, e0 - p);
            int j = 0;
            for (; j + 3 < cnt; j += 4) {
                int a0 = __shfl(sN, j), a1 = __shfl(sN, j + 1);
                int a2 = __shfl(sN, j + 2), a3 = __shfl(sN, j + 3);
                float q0 = __shfl(wN, j), q1 = __shfl(wN, j + 1);
                float q2 = __shfl(wN, j + 2), q3 = __shfl(wN, j + 3);
                float g0 = h1[a0 * DHID + lane];
                float g1 = h1[a1 * DHID + lane];
                float g2 = h1[a2 * DHID + lane];
                float g3 = h1[a3 * DHID + lane];
                acc = fmaf(q0, g0, acc);
                acc = fmaf(q1, g1, acc);
                acc = fmaf(q2, g2, acc);
                acc = fmaf(q3, g3, acc);
            }
            for (; j < cnt; ++j) {
                int a = __shfl(sN, j);
                float q = __shfl(wN, j);
                acc = fmaf(q, h1[a * DHID + lane], acc);
            }
        }
        acc = fmaxf(acc + bias, 0.0f);        // + b1, ReLU
        float o0 = acc * w2a, o1 = acc * w2b; // @ W2
        for (int off = 32; off > 0; off >>= 1) {
            o0 += __shfl_xor(o0, off);
            o1 += __shfl_xor(o1, off);
        }
        if (lane == 0) {
            h2[i * 2]     = o0;
            h2[i * 2 + 1] = o1;
        }
    }
}

// ------- K10: layer-2 propagate: out = agg(norm * h2) + b2 ---------
// one wave per node; lanes parallel over edges, float2 gathers
__global__ __launch_bounds__(256) void k_prop2(const float* __restrict__ h2,
                                               const int* __restrict__ rp,
                                               const int* __restrict__ cs,
                                               const float* __restrict__ cn,
                                               const float* __restrict__ dinv,
                                               const float* __restrict__ b2,
                                               float* __restrict__ out, int N) {
    const float2* h2v = (const float2*)h2;
    int lane = threadIdx.x & 63;
    int wid = (blockIdx.x * 256 + threadIdx.x) >> 6;
    int nw = (gridDim.x * 256) >> 6;
    float b20 = b2[0], b21 = b2[1];
    for (int i = wid; i < N; i += nw) {
        int s0 = rp[i], e0 = rp[i + 1];
        float a0 = 0.0f, a1 = 0.0f;
        for (int p = s0 + lane; p < e0; p += 64) {
            int s = cs[p];
            float w = cn[p];
            float2 hv = h2v[s];
            a0 = fmaf(w, hv.x, a0);
            a1 = fmaf(w, hv.y, a1);
        }
        for (int off = 32; off > 0; off >>= 1) {
            a0 += __shfl_xor(a0, off);
            a1 += __shfl_xor(a1, off);
        }
        if (lane == 0) {
            float di = dinv[i];
            float sl = di * di;
            out[i * 2]     = a0 + sl * h2[i * 2]     + b20;
            out[i * 2 + 1] = a1 + sl * h2[i * 2 + 1] + b21;
        }
    }
}

extern "C" void kernel_launch(void* const* d_in, const int* in_sizes, int n_in,
                              void* d_out, int out_size, void* d_ws, size_t ws_size,
                              hipStream_t stream) {
    const float* x  = (const float*)d_in[0];
    const int*   ei = (const int*)d_in[1];     // int32 per harness contract
    const float* ew = (const float*)d_in[2];
    const float* W1 = (const float*)d_in[3];
    const float* b1 = (const float*)d_in[4];
    const float* W2 = (const float*)d_in[5];
    const float* b2 = (const float*)d_in[6];
    float* out = (float*)d_out;

    const int N = in_sizes[0] / DIN;   // 100000
    const int E = in_sizes[2];         // 3200000

    // workspace layout (all 4-byte elems; h2 kept 8B-aligned)
    float* deg  = (float*)d_ws;          // N  (becomes dinv in place)
    int*   cnt  = (int*)(deg + N);       // N
    int*   rp   = cnt + N;               // N+8 (padded for alignment)
    int*   nxt  = rp + (N + 8);          // N
    int*   bsum = nxt + N;               // 1024
    int*   cs   = bsum + 1024;           // E
    float* cn   = (float*)(cs + E);      // E
    float* h1   = cn + E;                // N*64
    float* h2   = h1 + (size_t)N * DHID; // N*2

    const int NB = (N + 255) / 256;      // 391 blocks for node-sized kernels
    const int EB = (E + 255) / 256;

    k_init<<<NB, 256, 0, stream>>>(deg, cnt, N);
    k_count<<<EB, 256, 0, stream>>>(ei, ew, deg, cnt, E);
    k_rsqrt<<<NB, 256, 0, stream>>>(deg, N);
    k_partial<<<NB, 256, 0, stream>>>(cnt, bsum, N);
    k_scan_bsum<<<1, 1024, 0, stream>>>(bsum, NB);
    k_rowptr<<<NB, 256, 0, stream>>>(cnt, bsum, rp, nxt, N);
    k_fill<<<EB, 256, 0, stream>>>(ei, ew, deg, nxt, cs, cn, E);

    const int G8 = 1024;
    const int iters = (N + G8 * 4 - 1) / (G8 * 4);
    k_gemm1<<<G8, 256, 0, stream>>>(x, W1, h1, N, iters);

    const int GW = (N * 64 + 255) / 256;   // one wave per node
    k_agg1<<<GW, 256, 0, stream>>>(h1, rp, cs, cn, deg, b1, W2, h2, N);
    k_prop2<<<GW, 256, 0, stream>>>(h2, rp, cs, cn, deg, b2, out, N);
}

// Round 3
// 669.425 us; speedup vs baseline: 1.3498x; 1.3498x over previous
//
#include <hip/hip_runtime.h>
#include <hip/hip_bf16.h>

// 2-layer GCN, N=100000 nodes, E=3.2M edges, dims 128 -> 64 -> 2, fp32.
// R3: device-scope atomics are memory-side on gfx950 (k_count showed 200MB
// write-through for 800KB of logical state). Reduced to ONE int atomic/edge:
//   rank[e] = atomicAdd(&cnt[dst],1)  (rank aliased into h1's dead space)
//   scan cnt -> rp;  fill at rp[dst]+rank[e] with plain stores
//   deg via coalesced segment-sum post-fill (no float atomics)

#define DIN  128
#define DHID 64

// ---------------- K1: cnt = 0 ----------------
__global__ void k_zero(int* cnt, int N) {
    int i = blockIdx.x * 256 + threadIdx.x;
    if (i < N) cnt[i] = 0;
}

// ---------------- K2: rank[e] = atomicAdd(cnt[dst], 1) -------------
__global__ void k_rank(const int* __restrict__ ei, int* cnt, int* rank, int E) {
    int e = blockIdx.x * 256 + threadIdx.x;
    if (e < E) {
        int d = ei[E + e];
        rank[e] = atomicAdd(&cnt[d], 1);
    }
}

// ---------------- K3: per-block partial sums of cnt ----------------
__global__ void k_partial(const int* __restrict__ cnt, int* bsum, int N) {
    __shared__ int sm[256];
    int i = blockIdx.x * 256 + threadIdx.x;
    sm[threadIdx.x] = (i < N) ? cnt[i] : 0;
    __syncthreads();
    for (int off = 128; off > 0; off >>= 1) {
        if (threadIdx.x < off) sm[threadIdx.x] += sm[threadIdx.x + off];
        __syncthreads();
    }
    if (threadIdx.x == 0) bsum[blockIdx.x] = sm[0];
}

// ---------------- K4: exclusive scan of block sums (1 block) -------
__global__ void k_scan_bsum(int* bsum, int NB) {
    __shared__ int sm[1024];
    int t = threadIdx.x;
    int v = (t < NB) ? bsum[t] : 0;
    sm[t] = v;
    __syncthreads();
    for (int off = 1; off < 1024; off <<= 1) {
        int add = (t >= off) ? sm[t - off] : 0;
        __syncthreads();
        sm[t] += add;
        __syncthreads();
    }
    if (t < NB) bsum[t] = sm[t] - v;  // exclusive
}

// ---------------- K5: row_ptr from scanned sums --------------------
__global__ void k_rowptr(const int* __restrict__ cnt, const int* __restrict__ bsum,
                         int* rp, int N) {
    __shared__ int sm[256];
    int i = blockIdx.x * 256 + threadIdx.x;
    int c = (i < N) ? cnt[i] : 0;
    sm[threadIdx.x] = c;
    __syncthreads();
    for (int off = 1; off < 256; off <<= 1) {
        int add = (threadIdx.x >= off) ? sm[threadIdx.x - off] : 0;
        __syncthreads();
        sm[threadIdx.x] += add;
        __syncthreads();
    }
    int excl = bsum[blockIdx.x] + sm[threadIdx.x] - c;
    if (i < N) {
        rp[i] = excl;
        if (i == N - 1) rp[N] = excl + c;
    }
}

// ---------------- K6: CSR fill, NO atomics -------------------------
__global__ void k_fill(const int* __restrict__ ei, const float* __restrict__ ew,
                       const int* __restrict__ rp, const int* __restrict__ rank,
                       int* cs, float* cw, int E) {
    int e = blockIdx.x * 256 + threadIdx.x;
    if (e < E) {
        int s = ei[e];
        int d = ei[E + e];
        int pos = rp[d] + rank[e];
        cs[pos] = s;
        cw[pos] = ew[e];
    }
}

// ---------------- K7: dinv[i] = rsqrt(1 + sum(cw row)) -------------
__global__ __launch_bounds__(256) void k_deg(const int* __restrict__ rp,
                                             const float* __restrict__ cw,
                                             float* __restrict__ dinv, int N) {
    int lane = threadIdx.x & 63;
    int i = (blockIdx.x * 256 + threadIdx.x) >> 6;
    if (i >= N) return;
    int s0 = rp[i], e0 = rp[i + 1];
    float sum = 0.0f;
    for (int p = s0 + lane; p < e0; p += 64) sum += cw[p];
    for (int off = 32; off > 0; off >>= 1) sum += __shfl_xor(sum, off);
    if (lane == 0) dinv[i] = rsqrtf(1.0f + sum);
}

// ---------------- K8: cn[p] = dinv[src]*ew*dinv[dst], in place -----
__global__ __launch_bounds__(256) void k_norm(const int* __restrict__ rp,
                                              const int* __restrict__ cs,
                                              const float* __restrict__ dinv,
                                              float* __restrict__ cw, int N) {
    int lane = threadIdx.x & 63;
    int i = (blockIdx.x * 256 + threadIdx.x) >> 6;
    if (i >= N) return;
    float di = dinv[i];
    int s0 = rp[i], e0 = rp[i + 1];
    for (int p = s0 + lane; p < e0; p += 64)
        cw[p] = dinv[cs[p]] * cw[p] * di;
}

// ---------------- K9: h1 = x @ W1  (N x 128 @ 128 x 64) ------------
__global__ __launch_bounds__(256) void k_gemm1(const float* __restrict__ x,
                                               const float* __restrict__ W1,
                                               float* __restrict__ h1,
                                               int N, int iters) {
    __shared__ float wlds[DIN * DHID];  // 32 KB
    __shared__ float xs[4][DIN];        // 2 KB
    for (int t = threadIdx.x; t < DIN * DHID; t += 256) wlds[t] = W1[t];
    __syncthreads();
    int g = threadIdx.x >> 6;
    int lane = threadIdx.x & 63;
    for (int it = 0; it < iters; ++it) {
        int r = blockIdx.x * 4 + g + it * gridDim.x * 4;
        if (r < N) {
            xs[g][lane]      = x[r * DIN + lane];
            xs[g][lane + 64] = x[r * DIN + 64 + lane];
        }
        __syncthreads();
        if (r < N) {
            float acc = 0.0f;
#pragma unroll 8
            for (int k = 0; k < DIN; ++k)
                acc = fmaf(xs[g][k], wlds[k * DHID + lane], acc);
            h1[r * DHID + lane] = acc;
        }
        __syncthreads();
    }
}

// ------- K10: fused layer-1 aggregate + bias + ReLU + @W2 ----------
// one wave per node; lane = feature dim (64)
__global__ __launch_bounds__(256) void k_agg1(const float* __restrict__ h1,
                                              const int* __restrict__ rp,
                                              const int* __restrict__ cs,
                                              const float* __restrict__ cn,
                                              const float* __restrict__ dinv,
                                              const float* __restrict__ b1,
                                              const float* __restrict__ W2,
                                              float* __restrict__ h2, int N) {
    int lane = threadIdx.x & 63;
    int wid = (blockIdx.x * 256 + threadIdx.x) >> 6;
    int nw = (gridDim.x * 256) >> 6;
    float bias = b1[lane];
    float w2a = W2[lane * 2];
    float w2b = W2[lane * 2 + 1];
    for (int i = wid; i < N; i += nw) {
        float di = dinv[i];
        float acc = di * di * h1[i * DHID + lane];
        int s0 = rp[i], e0 = rp[i + 1];
        for (int p = s0; p < e0; p += 64) {
            int idx = p + lane;
            bool v = idx < e0;
            int sN = v ? cs[idx] : 0;
            float wN = v ? cn[idx] : 0.0f;
            int cnt = min(64, e0 - p);
            int j = 0;
            for (; j + 3 < cnt; j += 4) {
                int a0 = __shfl(sN, j), a1 = __shfl(sN, j + 1);
                int a2 = __shfl(sN, j + 2), a3 = __shfl(sN, j + 3);
                float q0 = __shfl(wN, j), q1 = __shfl(wN, j + 1);
                float q2 = __shfl(wN, j + 2), q3 = __shfl(wN, j + 3);
                float g0 = h1[a0 * DHID + lane];
                float g1 = h1[a1 * DHID + lane];
                float g2 = h1[a2 * DHID + lane];
                float g3 = h1[a3 * DHID + lane];
                acc = fmaf(q0, g0, acc);
                acc = fmaf(q1, g1, acc);
                acc = fmaf(q2, g2, acc);
                acc = fmaf(q3, g3, acc);
            }
            for (; j < cnt; ++j) {
                int a = __shfl(sN, j);
                float q = __shfl(wN, j);
                acc = fmaf(q, h1[a * DHID + lane], acc);
            }
        }
        acc = fmaxf(acc + bias, 0.0f);        // + b1, ReLU
        float o0 = acc * w2a, o1 = acc * w2b; // @ W2
        for (int off = 32; off > 0; off >>= 1) {
            o0 += __shfl_xor(o0, off);
            o1 += __shfl_xor(o1, off);
        }
        if (lane == 0) {
            h2[i * 2]     = o0;
            h2[i * 2 + 1] = o1;
        }
    }
}

// ------- K11: layer-2 propagate: out = agg(norm * h2) + b2 ---------
__global__ __launch_bounds__(256) void k_prop2(const float* __restrict__ h2,
                                               const int* __restrict__ rp,
                                               const int* __restrict__ cs,
                                               const float* __restrict__ cn,
                                               const float* __restrict__ dinv,
                                               const float* __restrict__ b2,
                                               float* __restrict__ out, int N) {
    const float2* h2v = (const float2*)h2;
    int lane = threadIdx.x & 63;
    int wid = (blockIdx.x * 256 + threadIdx.x) >> 6;
    int nw = (gridDim.x * 256) >> 6;
    float b20 = b2[0], b21 = b2[1];
    for (int i = wid; i < N; i += nw) {
        int s0 = rp[i], e0 = rp[i + 1];
        float a0 = 0.0f, a1 = 0.0f;
        for (int p = s0 + lane; p < e0; p += 64) {
            int s = cs[p];
            float w = cn[p];
            float2 hv = h2v[s];
            a0 = fmaf(w, hv.x, a0);
            a1 = fmaf(w, hv.y, a1);
        }
        for (int off = 32; off > 0; off >>= 1) {
            a0 += __shfl_xor(a0, off);
            a1 += __shfl_xor(a1, off);
        }
        if (lane == 0) {
            float di = dinv[i];
            float sl = di * di;
            out[i * 2]     = a0 + sl * h2[i * 2]     + b20;
            out[i * 2 + 1] = a1 + sl * h2[i * 2 + 1] + b21;
        }
    }
}

extern "C" void kernel_launch(void* const* d_in, const int* in_sizes, int n_in,
                              void* d_out, int out_size, void* d_ws, size_t ws_size,
                              hipStream_t stream) {
    const float* x  = (const float*)d_in[0];
    const int*   ei = (const int*)d_in[1];     // int32 per harness contract
    const float* ew = (const float*)d_in[2];
    const float* W1 = (const float*)d_in[3];
    const float* b1 = (const float*)d_in[4];
    const float* W2 = (const float*)d_in[5];
    const float* b2 = (const float*)d_in[6];
    float* out = (float*)d_out;

    const int N = in_sizes[0] / DIN;   // 100000
    const int E = in_sizes[2];         // 3200000

    // workspace layout (4-byte elems; h2 8B-aligned)
    float* dinv = (float*)d_ws;          // N
    int*   cnt  = (int*)(dinv + N);      // N
    int*   rp   = cnt + N;               // N+8 (pad)
    int*   bsum = rp + (N + 8);          // 1024
    int*   cs   = bsum + 1024;           // E
    float* cw   = (float*)(cs + E);      // E   (raw ew, then norm in place)
    float* h1   = cw + E;                // N*64  (first E ints = rank, dead after k_fill)
    float* h2   = h1 + (size_t)N * DHID; // N*2
    int*   rank = (int*)h1;              // alias: E <= N*64

    const int NB = (N + 255) / 256;
    const int EB = (E + 255) / 256;
    const int GW = (N * 64 + 255) / 256;   // one wave per node

    k_zero<<<NB, 256, 0, stream>>>(cnt, N);
    k_rank<<<EB, 256, 0, stream>>>(ei, cnt, rank, E);
    k_partial<<<NB, 256, 0, stream>>>(cnt, bsum, N);
    k_scan_bsum<<<1, 1024, 0, stream>>>(bsum, NB);
    k_rowptr<<<NB, 256, 0, stream>>>(cnt, bsum, rp, N);
    k_fill<<<EB, 256, 0, stream>>>(ei, ew, rp, rank, cs, cw, E);
    k_deg<<<GW, 256, 0, stream>>>(rp, cw, dinv, N);
    k_norm<<<GW, 256, 0, stream>>>(rp, cs, dinv, cw, N);

    const int G8 = 1024;
    const int iters = (N + G8 * 4 - 1) / (G8 * 4);
    k_gemm1<<<G8, 256, 0, stream>>>(x, W1, h1, N, iters);

    k_agg1<<<GW, 256, 0, stream>>>(h1, rp, cs, cw, dinv, b1, W2, h2, N);
    k_prop2<<<GW, 256, 0, stream>>>(h2, rp, cs, cw, dinv, b2, out, N);
}

// Round 6
// 603.801 us; speedup vs baseline: 1.4965x; 1.1087x over previous
//
#include <hip/hip_runtime.h>
#include <hip/hip_bf16.h>
#include <hip/hip_fp16.h>

// 2-layer GCN, N=100000 nodes, E=3.2M edges, dims 128 -> 64 -> 2, fp32.
// R6: R4/R5's absmax 1.3e-2 was a DIVERGENT-SHUFFLE bug, not quantization:
// __shfl inside `if (jj < cnt)` read from an exec-masked-off source lane
// (odd cnt >= 33, last edge) -> ds_bpermute returns undefined -> edge
// dropped. Fix: shuffles are unconditional (all 64 lanes active, clamped
// src index); invalid slots predicated by we=0. h1 stays fp16.

#define DIN  128
#define DHID 64

// ---------------- K1: cnt = 0 ----------------
__global__ void k_zero(int* cnt, int N) {
    int i = blockIdx.x * 256 + threadIdx.x;
    if (i < N) cnt[i] = 0;
}

// ---------------- K2: rank[e] = atomicAdd(cnt[dst], 1) -------------
__global__ void k_rank(const int* __restrict__ ei, int* cnt, int* rank, int E) {
    int e = blockIdx.x * 256 + threadIdx.x;
    if (e < E) {
        int d = ei[E + e];
        rank[e] = atomicAdd(&cnt[d], 1);
    }
}

// ---------------- K3: per-block partial sums of cnt ----------------
__global__ void k_partial(const int* __restrict__ cnt, int* bsum, int N) {
    __shared__ int sm[256];
    int i = blockIdx.x * 256 + threadIdx.x;
    sm[threadIdx.x] = (i < N) ? cnt[i] : 0;
    __syncthreads();
    for (int off = 128; off > 0; off >>= 1) {
        if (threadIdx.x < off) sm[threadIdx.x] += sm[threadIdx.x + off];
        __syncthreads();
    }
    if (threadIdx.x == 0) bsum[blockIdx.x] = sm[0];
}

// ---------------- K4: exclusive scan of block sums (1 block) -------
__global__ void k_scan_bsum(int* bsum, int NB) {
    __shared__ int sm[1024];
    int t = threadIdx.x;
    int v = (t < NB) ? bsum[t] : 0;
    sm[t] = v;
    __syncthreads();
    for (int off = 1; off < 1024; off <<= 1) {
        int add = (t >= off) ? sm[t - off] : 0;
        __syncthreads();
        sm[t] += add;
        __syncthreads();
    }
    if (t < NB) bsum[t] = sm[t] - v;  // exclusive
}

// ---------------- K5: row_ptr from scanned sums --------------------
__global__ void k_rowptr(const int* __restrict__ cnt, const int* __restrict__ bsum,
                         int* rp, int N) {
    __shared__ int sm[256];
    int i = blockIdx.x * 256 + threadIdx.x;
    int c = (i < N) ? cnt[i] : 0;
    sm[threadIdx.x] = c;
    __syncthreads();
    for (int off = 1; off < 256; off <<= 1) {
        int add = (threadIdx.x >= off) ? sm[threadIdx.x - off] : 0;
        __syncthreads();
        sm[threadIdx.x] += add;
        __syncthreads();
    }
    int excl = bsum[blockIdx.x] + sm[threadIdx.x] - c;
    if (i < N) {
        rp[i] = excl;
        if (i == N - 1) rp[N] = excl + c;
    }
}

// ---------------- K6: CSR fill, NO atomics, ONE int2 scatter -------
__global__ void k_fill(const int* __restrict__ ei, const float* __restrict__ ew,
                       const int* __restrict__ rp, const int* __restrict__ rank,
                       int2* __restrict__ csw, int E) {
    int e = blockIdx.x * 256 + threadIdx.x;
    if (e < E) {
        int s = ei[e];
        int d = ei[E + e];
        int pos = rp[d] + rank[e];
        csw[pos] = make_int2(s, __float_as_int(ew[e]));
    }
}

// ---------------- K7: dinv[i] = rsqrt(1 + sum(w row)) --------------
__global__ __launch_bounds__(256) void k_deg(const int* __restrict__ rp,
                                             const int2* __restrict__ csw,
                                             float* __restrict__ dinv, int N) {
    int lane = threadIdx.x & 63;
    int i = (blockIdx.x * 256 + threadIdx.x) >> 6;
    if (i >= N) return;
    int s0 = rp[i], e0 = rp[i + 1];
    float sum = 0.0f;
    for (int p = s0 + lane; p < e0; p += 64) sum += __int_as_float(csw[p].y);
    for (int off = 32; off > 0; off >>= 1) sum += __shfl_xor(sum, off);
    if (lane == 0) dinv[i] = rsqrtf(1.0f + sum);
}

// ---------------- K8: w <- dinv[src]*w*dinv[dst], in place ---------
__global__ __launch_bounds__(256) void k_norm(const int* __restrict__ rp,
                                              const float* __restrict__ dinv,
                                              int2* __restrict__ csw, int N) {
    int lane = threadIdx.x & 63;
    int i = (blockIdx.x * 256 + threadIdx.x) >> 6;
    if (i >= N) return;
    float di = dinv[i];
    int s0 = rp[i], e0 = rp[i + 1];
    for (int p = s0 + lane; p < e0; p += 64) {
        int2 v = csw[p];
        float w = __int_as_float(v.y);
        csw[p] = make_int2(v.x, __float_as_int(dinv[v.x] * w * di));
    }
}

// ---------------- K9: h1 = fp16(x @ W1)  (N x 128 @ 128 x 64) ------
__global__ __launch_bounds__(256) void k_gemm1(const float* __restrict__ x,
                                               const float* __restrict__ W1,
                                               __half* __restrict__ h1,
                                               int N, int iters) {
    __shared__ float wlds[DIN * DHID];  // 32 KB
    __shared__ float xs[4][DIN];        // 2 KB
    for (int t = threadIdx.x; t < DIN * DHID; t += 256) wlds[t] = W1[t];
    __syncthreads();
    int g = threadIdx.x >> 6;
    int lane = threadIdx.x & 63;
    for (int it = 0; it < iters; ++it) {
        int r = blockIdx.x * 4 + g + it * gridDim.x * 4;
        if (r < N) {
            xs[g][lane]      = x[r * DIN + lane];
            xs[g][lane + 64] = x[r * DIN + 64 + lane];
        }
        __syncthreads();
        if (r < N) {
            float acc = 0.0f;
#pragma unroll 8
            for (int k = 0; k < DIN; ++k)
                acc = fmaf(xs[g][k], wlds[k * DHID + lane], acc);
            h1[r * DHID + lane] = __float2half(acc);
        }
        __syncthreads();
    }
}

// ------- K10: fused layer-1 aggregate + bias + ReLU + @W2 ----------
// one wave per node; 32 lanes x half2 cover 64 feats; 2 edges/iter.
// Shuffles are UNCONDITIONAL (all lanes active) — predication via we=0.
__global__ __launch_bounds__(256) void k_agg1(const __half2* __restrict__ h1v,
                                              const int* __restrict__ rp,
                                              const int2* __restrict__ csw,
                                              const float* __restrict__ dinv,
                                              const float* __restrict__ b1,
                                              const float* __restrict__ W2,
                                              float* __restrict__ h2, int N) {
    int lane = threadIdx.x & 63;
    int sl   = lane & 31;          // feature pair index: feats {2sl, 2sl+1}
    int half = lane >> 5;          // which edge of the pair this lane handles
    int wid = (blockIdx.x * 256 + threadIdx.x) >> 6;
    int nw  = (gridDim.x * 256) >> 6;
    int f0 = 2 * sl, f1 = 2 * sl + 1;
    float bias0 = b1[f0], bias1 = b1[f1];
    float w2_00 = W2[f0 * 2], w2_01 = W2[f0 * 2 + 1];
    float w2_10 = W2[f1 * 2], w2_11 = W2[f1 * 2 + 1];

    for (int i = wid; i < N; i += nw) {
        float a0 = 0.0f, a1 = 0.0f;
        int s0 = rp[i], e0 = rp[i + 1];
        for (int p = s0; p < e0; p += 64) {
            int idx = p + lane;
            bool v = idx < e0;
            int2 ed = v ? csw[idx] : make_int2(0, 0);
            int   sN = ed.x;
            float wN = __int_as_float(ed.y);
            int cnt = min(64, e0 - p);
            for (int j = 0; j < cnt; j += 2) {
                int jj = j + half;
                bool ok = jj < cnt;
                int src = ok ? jj : 0;          // clamp to an active lane
                int   se = __shfl(sN, src);     // all 64 lanes execute
                float we = __shfl(wN, src);
                we = ok ? we : 0.0f;            // predicate the accumulate
                float2 f = __half22float2(h1v[se * 32 + sl]);
                a0 = fmaf(we, f.x, a0);
                a1 = fmaf(we, f.y, a1);
            }
        }
        // combine the two edge-halves (lanes sl and sl+32)
        a0 += __shfl_xor(a0, 32);
        a1 += __shfl_xor(a1, 32);
        // self-loop term
        {
            float di = dinv[i];
            float sw = di * di;
            float2 f = __half22float2(h1v[i * 32 + sl]);
            a0 = fmaf(sw, f.x, a0);
            a1 = fmaf(sw, f.y, a1);
        }
        a0 = fmaxf(a0 + bias0, 0.0f);
        a1 = fmaxf(a1 + bias1, 0.0f);
        float o0 = a0 * w2_00 + a1 * w2_10;
        float o1 = a0 * w2_01 + a1 * w2_11;
        for (int off = 16; off > 0; off >>= 1) {
            o0 += __shfl_xor(o0, off);
            o1 += __shfl_xor(o1, off);
        }
        if (lane == 0) {
            h2[i * 2]     = o0;
            h2[i * 2 + 1] = o1;
        }
    }
}

// ------- K11: layer-2 propagate: out = agg(norm * h2) + b2 ---------
__global__ __launch_bounds__(256) void k_prop2(const float* __restrict__ h2,
                                               const int* __restrict__ rp,
                                               const int2* __restrict__ csw,
                                               const float* __restrict__ dinv,
                                               const float* __restrict__ b2,
                                               float* __restrict__ out, int N) {
    const float2* h2v = (const float2*)h2;
    int lane = threadIdx.x & 63;
    int wid = (blockIdx.x * 256 + threadIdx.x) >> 6;
    int nw = (gridDim.x * 256) >> 6;
    float b20 = b2[0], b21 = b2[1];
    for (int i = wid; i < N; i += nw) {
        int s0 = rp[i], e0 = rp[i + 1];
        float a0 = 0.0f, a1 = 0.0f;
        for (int p = s0 + lane; p < e0; p += 64) {
            int2 ed = csw[p];
            float w = __int_as_float(ed.y);
            float2 hv = h2v[ed.x];
            a0 = fmaf(w, hv.x, a0);
            a1 = fmaf(w, hv.y, a1);
        }
        for (int off = 32; off > 0; off >>= 1) {
            a0 += __shfl_xor(a0, off);
            a1 += __shfl_xor(a1, off);
        }
        if (lane == 0) {
            float di = dinv[i];
            float sl = di * di;
            out[i * 2]     = a0 + sl * h2[i * 2]     + b20;
            out[i * 2 + 1] = a1 + sl * h2[i * 2 + 1] + b21;
        }
    }
}

extern "C" void kernel_launch(void* const* d_in, const int* in_sizes, int n_in,
                              void* d_out, int out_size, void* d_ws, size_t ws_size,
                              hipStream_t stream) {
    const float* x  = (const float*)d_in[0];
    const int*   ei = (const int*)d_in[1];     // int32 per harness contract
    const float* ew = (const float*)d_in[2];
    const float* W1 = (const float*)d_in[3];
    const float* b1 = (const float*)d_in[4];
    const float* W2 = (const float*)d_in[5];
    const float* b2 = (const float*)d_in[6];
    float* out = (float*)d_out;

    const int N = in_sizes[0] / DIN;   // 100000
    const int E = in_sizes[2];         // 3200000

    // workspace layout (8B alignment for int2/float2/half2 users)
    float* dinv = (float*)d_ws;               // N
    int*   cnt  = (int*)(dinv + N);           // N
    int*   rp   = cnt + N;                    // N+8 (pad keeps csw 8B-aligned)
    int*   bsum = rp + (N + 8);               // 1024
    int2*  csw  = (int2*)(bsum + 1024);       // E pairs (25.6 MB)
    __half* h1  = (__half*)(csw + E);         // N*64 fp16 (12.8 MB)
    float* h2   = (float*)(h1 + (size_t)N * DHID);    // N*2
    int*   rank = (int*)(h2 + 2 * N);         // E  (12.8 MB)

    const int NB = (N + 255) / 256;
    const int EB = (E + 255) / 256;
    const int GW = (N * 64 + 255) / 256;   // one wave per node

    k_zero<<<NB, 256, 0, stream>>>(cnt, N);
    k_rank<<<EB, 256, 0, stream>>>(ei, cnt, rank, E);
    k_partial<<<NB, 256, 0, stream>>>(cnt, bsum, N);
    k_scan_bsum<<<1, 1024, 0, stream>>>(bsum, NB);
    k_rowptr<<<NB, 256, 0, stream>>>(cnt, bsum, rp, N);
    k_fill<<<EB, 256, 0, stream>>>(ei, ew, rp, rank, csw, E);
    k_deg<<<GW, 256, 0, stream>>>(rp, csw, dinv, N);
    k_norm<<<GW, 256, 0, stream>>>(rp, dinv, csw, N);

    const int G8 = 1024;
    const int iters = (N + G8 * 4 - 1) / (G8 * 4);
    k_gemm1<<<G8, 256, 0, stream>>>(x, W1, h1, N, iters);

    k_agg1<<<GW, 256, 0, stream>>>((const __half2*)h1, rp, csw, dinv, b1, W2, h2, N);
    k_prop2<<<GW, 256, 0, stream>>>(h2, rp, csw, dinv, b2, out, N);
}

// Round 7
// 549.127 us; speedup vs baseline: 1.6455x; 1.0996x over previous
//
#include <hip/hip_runtime.h>
#include <hip/hip_bf16.h>
#include <hip/hip_fp16.h>

// 2-layer GCN, N=100000 nodes, E=3.2M edges, dims 128 -> 64 -> 2, fp32.
// R7: device atomics capped at ~22 G ops/s (k_rank 145us, k_count 278us both
// hit it). CSR build rewritten as a 2-level bucket counting sort using ONLY
// LDS atomics: hist(chunk x bucket) -> matrix scan -> cell-contiguous
// scatter -> per-bucket build (rp, dinv, csw placement in an L2-resident
// window). k_norm folded into agg/prop via on-the-fly dinv[src] (L2-hit).

#define DIN  128
#define DHID 64

// ---------------- K1: per-chunk coarse histogram (LDS only) --------
__global__ __launch_bounds__(256) void k_hist(const int* __restrict__ ei,
                                              int* __restrict__ hist,
                                              int E, int chunk, int B) {
    __shared__ int h[512];
    for (int t = threadIdx.x; t < B; t += 256) h[t] = 0;
    __syncthreads();
    int c = blockIdx.x;
    int e0 = c * chunk, e1 = min(E, e0 + chunk);
    for (int e = e0 + threadIdx.x; e < e1; e += 256)
        atomicAdd(&h[ei[E + e] >> 8], 1);
    __syncthreads();
    for (int t = threadIdx.x; t < B; t += 256) hist[c * B + t] = h[t];
}

// ---------------- K2: matrix scan -> cell offsets + bucket bases ---
// hist[c][b] becomes absolute start of cell (c,b); bb[b] = bucket base.
__global__ void k_mscan(int* __restrict__ hist, int* __restrict__ bb,
                        int C, int B) {
    __shared__ int sm[512];
    int t = threadIdx.x;
    int run = 0;
    if (t < B) {
        for (int c = 0; c < C; ++c) {
            int idx = c * B + t;
            int v = hist[idx];
            hist[idx] = run;      // within-bucket prefix over chunks
            run += v;
        }
    }
    sm[t] = (t < B) ? run : 0;    // tot_b
    __syncthreads();
    for (int off = 1; off < 512; off <<= 1) {
        int add = (t >= off) ? sm[t - off] : 0;
        __syncthreads();
        sm[t] += add;
        __syncthreads();
    }
    if (t < B) {
        int excl = sm[t] - run;   // bucket base
        bb[t] = excl;
        if (t == B - 1) bb[B] = sm[t];   // = E
        for (int c = 0; c < C; ++c) hist[c * B + t] += excl;
    }
}

// ---------------- K3: scatter edges into bucket-sorted ebuf --------
// ebuf entry: {(local_node << 24) | src, w_bits}; cell-contiguous writes.
__global__ __launch_bounds__(256) void k_scatter(const int* __restrict__ ei,
                                                 const float* __restrict__ ew,
                                                 const int* __restrict__ hist,
                                                 int2* __restrict__ ebuf,
                                                 int E, int chunk, int B) {
    __shared__ int cur[512];
    int c = blockIdx.x;
    for (int t = threadIdx.x; t < B; t += 256) cur[t] = hist[c * B + t];
    __syncthreads();
    int e0 = c * chunk, e1 = min(E, e0 + chunk);
    for (int e = e0 + threadIdx.x; e < e1; e += 256) {
        int s = ei[e];
        int d = ei[E + e];
        float w = ew[e];
        int b = d >> 8;
        int pos = atomicAdd(&cur[b], 1);   // LDS atomic
        ebuf[pos] = make_int2(s | ((d & 255) << 24), __float_as_int(w));
    }
}

// ---------------- K4: per-bucket CSR build (rp, dinv, csw) ---------
__global__ __launch_bounds__(256) void k_build(const int2* __restrict__ ebuf,
                                               const int* __restrict__ bb,
                                               int* __restrict__ rp,
                                               float* __restrict__ dinv,
                                               int2* __restrict__ csw,
                                               int N, int E) {
    __shared__ int   cnt[256];
    __shared__ float dsum[256];
    __shared__ int   lrp[256];
    __shared__ int   cur[256];
    __shared__ int   sm[256];
    int b = blockIdx.x, t = threadIdx.x;
    cnt[t] = 0; dsum[t] = 0.0f; cur[t] = 0;
    __syncthreads();
    int p0 = bb[b], p1 = bb[b + 1];
    for (int p = p0 + t; p < p1; p += 256) {
        int2 v = ebuf[p];
        int ln = ((unsigned)v.x) >> 24;
        atomicAdd(&cnt[ln], 1);
        atomicAdd(&dsum[ln], __int_as_float(v.y));
    }
    __syncthreads();
    int cv = cnt[t];
    sm[t] = cv;
    __syncthreads();
    for (int off = 1; off < 256; off <<= 1) {
        int add = (t >= off) ? sm[t - off] : 0;
        __syncthreads();
        sm[t] += add;
        __syncthreads();
    }
    lrp[t] = sm[t] - cv + p0;     // absolute csw base for local node t
    __syncthreads();
    int d = (b << 8) + t;
    if (d < N) {
        rp[d]   = lrp[t];
        dinv[d] = rsqrtf(1.0f + dsum[t]);
    }
    if (b == 0 && t == 0) rp[N] = E;
    for (int p = p0 + t; p < p1; p += 256) {
        int2 v = ebuf[p];
        int ln = ((unsigned)v.x) >> 24;
        int r = atomicAdd(&cur[ln], 1);   // LDS atomic
        csw[lrp[ln] + r] = make_int2(v.x & 0xFFFFFF, v.y);  // raw w
    }
}

// ---------------- K5: h1 = fp16(x @ W1)  (N x 128 @ 128 x 64) ------
__global__ __launch_bounds__(256) void k_gemm1(const float* __restrict__ x,
                                               const float* __restrict__ W1,
                                               __half* __restrict__ h1,
                                               int N, int iters) {
    __shared__ float wlds[DIN * DHID];  // 32 KB
    __shared__ float xs[4][DIN];        // 2 KB
    for (int t = threadIdx.x; t < DIN * DHID; t += 256) wlds[t] = W1[t];
    __syncthreads();
    int g = threadIdx.x >> 6;
    int lane = threadIdx.x & 63;
    for (int it = 0; it < iters; ++it) {
        int r = blockIdx.x * 4 + g + it * gridDim.x * 4;
        if (r < N) {
            xs[g][lane]      = x[r * DIN + lane];
            xs[g][lane + 64] = x[r * DIN + 64 + lane];
        }
        __syncthreads();
        if (r < N) {
            float acc = 0.0f;
#pragma unroll 8
            for (int k = 0; k < DIN; ++k)
                acc = fmaf(xs[g][k], wlds[k * DHID + lane], acc);
            h1[r * DHID + lane] = __float2half(acc);
        }
        __syncthreads();
    }
}

// ------- K6: fused layer-1 aggregate + bias + ReLU + @W2 -----------
// one wave per node; 32 lanes x half2 cover 64 feats; 2 edges/iter.
// norm folded: we = w * dinv[src]; final = dinv_i*(edge_sum + dinv_i*self).
__global__ __launch_bounds__(256) void k_agg1(const __half2* __restrict__ h1v,
                                              const int* __restrict__ rp,
                                              const int2* __restrict__ csw,
                                              const float* __restrict__ dinv,
                                              const float* __restrict__ b1,
                                              const float* __restrict__ W2,
                                              float* __restrict__ h2, int N) {
    int lane = threadIdx.x & 63;
    int sl   = lane & 31;          // feature pair index: feats {2sl, 2sl+1}
    int half = lane >> 5;          // which edge of the pair this lane handles
    int wid = (blockIdx.x * 256 + threadIdx.x) >> 6;
    int nw  = (gridDim.x * 256) >> 6;
    int f0 = 2 * sl, f1 = 2 * sl + 1;
    float bias0 = b1[f0], bias1 = b1[f1];
    float w2_00 = W2[f0 * 2], w2_01 = W2[f0 * 2 + 1];
    float w2_10 = W2[f1 * 2], w2_11 = W2[f1 * 2 + 1];

    for (int i = wid; i < N; i += nw) {
        float a0 = 0.0f, a1 = 0.0f;
        int s0 = rp[i], e0 = rp[i + 1];
        for (int p = s0; p < e0; p += 64) {
            int idx = p + lane;
            bool v = idx < e0;
            int2 ed = v ? csw[idx] : make_int2(0, 0);
            int   sN = ed.x;
            float wN = __int_as_float(ed.y) * dinv[sN];  // raw w * dinv[src]
            int cnt = min(64, e0 - p);
            for (int j = 0; j < cnt; j += 2) {
                int jj = j + half;
                bool ok = jj < cnt;
                int src = ok ? jj : 0;          // clamp to an active lane
                int   se = __shfl(sN, src);     // all 64 lanes execute
                float we = __shfl(wN, src);
                we = ok ? we : 0.0f;            // predicate the accumulate
                float2 f = __half22float2(h1v[se * 32 + sl]);
                a0 = fmaf(we, f.x, a0);
                a1 = fmaf(we, f.y, a1);
            }
        }
        // combine the two edge-halves (lanes sl and sl+32)
        a0 += __shfl_xor(a0, 32);
        a1 += __shfl_xor(a1, 32);
        // self-loop + dst-side norm: di*(edge_sum + di*self)
        float di = dinv[i];
        float2 f = __half22float2(h1v[i * 32 + sl]);
        a0 = (a0 + di * f.x) * di;
        a1 = (a1 + di * f.y) * di;
        a0 = fmaxf(a0 + bias0, 0.0f);
        a1 = fmaxf(a1 + bias1, 0.0f);
        float o0 = a0 * w2_00 + a1 * w2_10;
        float o1 = a0 * w2_01 + a1 * w2_11;
        for (int off = 16; off > 0; off >>= 1) {
            o0 += __shfl_xor(o0, off);
            o1 += __shfl_xor(o1, off);
        }
        if (lane == 0) {
            h2[i * 2]     = o0;
            h2[i * 2 + 1] = o1;
        }
    }
}

// ------- K7: layer-2 propagate: out = di*(sum + di*self) + b2 ------
__global__ __launch_bounds__(256) void k_prop2(const float* __restrict__ h2,
                                               const int* __restrict__ rp,
                                               const int2* __restrict__ csw,
                                               const float* __restrict__ dinv,
                                               const float* __restrict__ b2,
                                               float* __restrict__ out, int N) {
    const float2* h2v = (const float2*)h2;
    int lane = threadIdx.x & 63;
    int wid = (blockIdx.x * 256 + threadIdx.x) >> 6;
    int nw = (gridDim.x * 256) >> 6;
    float b20 = b2[0], b21 = b2[1];
    for (int i = wid; i < N; i += nw) {
        int s0 = rp[i], e0 = rp[i + 1];
        float a0 = 0.0f, a1 = 0.0f;
        for (int p = s0 + lane; p < e0; p += 64) {
            int2 ed = csw[p];
            float w = __int_as_float(ed.y) * dinv[ed.x];  // raw w * dinv[src]
            float2 hv = h2v[ed.x];
            a0 = fmaf(w, hv.x, a0);
            a1 = fmaf(w, hv.y, a1);
        }
        for (int off = 32; off > 0; off >>= 1) {
            a0 += __shfl_xor(a0, off);
            a1 += __shfl_xor(a1, off);
        }
        if (lane == 0) {
            float di = dinv[i];
            out[i * 2]     = di * (a0 + di * h2[i * 2])     + b20;
            out[i * 2 + 1] = di * (a1 + di * h2[i * 2 + 1]) + b21;
        }
    }
}

extern "C" void kernel_launch(void* const* d_in, const int* in_sizes, int n_in,
                              void* d_out, int out_size, void* d_ws, size_t ws_size,
                              hipStream_t stream) {
    const float* x  = (const float*)d_in[0];
    const int*   ei = (const int*)d_in[1];     // int32 per harness contract
    const float* ew = (const float*)d_in[2];
    const float* W1 = (const float*)d_in[3];
    const float* b1 = (const float*)d_in[4];
    const float* W2 = (const float*)d_in[5];
    const float* b2 = (const float*)d_in[6];
    float* out = (float*)d_out;

    const int N = in_sizes[0] / DIN;   // 100000
    const int E = in_sizes[2];         // 3200000

    const int C = 256;                 // edge chunks
    const int B = (N + 255) >> 8;      // 391 coarse buckets (256 nodes each)
    const int chunk = (E + C - 1) / C;

    // workspace layout (52.4 MB; ebuf aliased by h1/h2 after k_build)
    char* w0 = (char*)d_ws;
    float* dinv = (float*)w0;                       // N floats
    int*   rp   = (int*)(dinv + N);                 // N+1 ints (+3 pad)
    int*   hist = rp + (N + 4);                     // C*B ints
    int*   bb   = hist + (size_t)C * B;             // B+1 ints
    size_t off_csw = ((size_t)((char*)(bb + B + 1) - w0) + 15) & ~(size_t)15;
    int2*  csw  = (int2*)(w0 + off_csw);            // E pairs (25.6 MB)
    int2*  ebuf = csw + E;                          // E pairs (25.6 MB)
    __half* h1  = (__half*)ebuf;                    // alias: N*64 fp16 (12.8 MB)
    float* h2   = (float*)(h1 + (size_t)N * DHID);  // alias: N*2 fp32

    k_hist<<<C, 256, 0, stream>>>(ei, hist, E, chunk, B);
    k_mscan<<<1, 512, 0, stream>>>(hist, bb, C, B);
    k_scatter<<<C, 256, 0, stream>>>(ei, ew, hist, ebuf, E, chunk, B);
    k_build<<<B, 256, 0, stream>>>(ebuf, bb, rp, dinv, csw, N, E);

    const int G8 = 1024;
    const int iters = (N + G8 * 4 - 1) / (G8 * 4);
    k_gemm1<<<G8, 256, 0, stream>>>(x, W1, h1, N, iters);

    const int GW = (N * 64 + 255) / 256;   // one wave per node
    k_agg1<<<GW, 256, 0, stream>>>((const __half2*)h1, rp, csw, dinv, b1, W2, h2, N);
    k_prop2<<<GW, 256, 0, stream>>>(h2, rp, csw, dinv, b2, out, N);
}

// Round 8
// 460.935 us; speedup vs baseline: 1.9603x; 1.1913x over previous
//
#include <hip/hip_runtime.h>
#include <hip/hip_bf16.h>
#include <hip/hip_fp16.h>

// 2-layer GCN, N=100000 nodes, E=3.2M edges, dims 128 -> 64 -> 2, fp32.
// R8: (1) k_agg1 rewritten with wave-uniform scalar edge loads: one
//     coalesced 128B fp16-row gather per edge, no shuffles/predication;
//     (2) single-block k_mscan replaced by parallel per-bucket scan
//     (hist bucket-major) + tiny total-scan;
//     (3) buckets = 128 nodes so k_build stages its edges in 40KB LDS
//     (no second global read of ebuf).

#define DIN  128
#define DHID 64
#define BSH  7                    // bucket shift: 128 nodes/bucket
#define BCAP 5000                 // LDS staging capacity (edges/bucket)

// ---------------- K1: per-chunk coarse histogram (LDS only) --------
__global__ __launch_bounds__(256) void k_hist(const int* __restrict__ ei,
                                              int* __restrict__ histT,
                                              int E, int chunk, int B, int C) {
    extern __shared__ int h[];
    for (int t = threadIdx.x; t < B; t += 256) h[t] = 0;
    __syncthreads();
    int c = blockIdx.x;
    int e0 = c * chunk, e1 = min(E, e0 + chunk);
    for (int e = e0 + threadIdx.x; e < e1; e += 256)
        atomicAdd(&h[ei[E + e] >> BSH], 1);
    __syncthreads();
    for (int t = threadIdx.x; t < B; t += 256) histT[(size_t)t * C + c] = h[t];
}

// ------- K2: per-bucket exclusive scan over its 256 chunk-cells ----
__global__ __launch_bounds__(256) void k_scan1(int* __restrict__ histT,
                                               int* __restrict__ tot, int C) {
    __shared__ int sm[256];
    int b = blockIdx.x, t = threadIdx.x;
    size_t base = (size_t)b * C;
    int v = histT[base + t];
    sm[t] = v;
    __syncthreads();
    for (int off = 1; off < 256; off <<= 1) {
        int add = (t >= off) ? sm[t - off] : 0;
        __syncthreads();
        sm[t] += add;
        __syncthreads();
    }
    histT[base + t] = sm[t] - v;          // exclusive within bucket
    if (t == 255) tot[b] = sm[t];
}

// ------- K3: exclusive scan of bucket totals -> bucket bases -------
__global__ __launch_bounds__(1024) void k_scan2(const int* __restrict__ tot,
                                                int* __restrict__ bb, int B) {
    __shared__ int sm[1024];
    int t = threadIdx.x;
    int v = (t < B) ? tot[t] : 0;
    sm[t] = v;
    __syncthreads();
    for (int off = 1; off < 1024; off <<= 1) {
        int add = (t >= off) ? sm[t - off] : 0;
        __syncthreads();
        sm[t] += add;
        __syncthreads();
    }
    if (t < B) {
        bb[t] = sm[t] - v;
        if (t == B - 1) bb[B] = sm[t];
    }
}

// ---------------- K4: scatter edges into bucket-sorted ebuf --------
// ebuf entry: {(local_node << 24) | src, w_bits}; cell-contiguous writes.
__global__ __launch_bounds__(256) void k_scatter(const int* __restrict__ ei,
                                                 const float* __restrict__ ew,
                                                 const int* __restrict__ histT,
                                                 const int* __restrict__ bb,
                                                 int2* __restrict__ ebuf,
                                                 int E, int chunk, int B, int C) {
    extern __shared__ int cur[];
    int c = blockIdx.x;
    for (int t = threadIdx.x; t < B; t += 256)
        cur[t] = histT[(size_t)t * C + c] + bb[t];
    __syncthreads();
    int e0 = c * chunk, e1 = min(E, e0 + chunk);
    for (int e = e0 + threadIdx.x; e < e1; e += 256) {
        int s = ei[e];
        int d = ei[E + e];
        float w = ew[e];
        int b = d >> BSH;
        int pos = atomicAdd(&cur[b], 1);   // LDS atomic
        ebuf[pos] = make_int2(s | ((d & 127) << 24), __float_as_int(w));
    }
}

// ---------------- K5: per-bucket CSR build (rp, dinv, csw) ---------
// edges staged in LDS (pass 2 reads LDS, not global).
__global__ __launch_bounds__(256) void k_build(const int2* __restrict__ ebuf,
                                               const int* __restrict__ bb,
                                               int* __restrict__ rp,
                                               float* __restrict__ dinv,
                                               int2* __restrict__ csw,
                                               int N, int E) {
    __shared__ int2  stage[BCAP];   // 40 KB
    __shared__ int   cnt[128];
    __shared__ float dsum[128];
    __shared__ int   lrp[128];
    __shared__ int   cur[128];
    __shared__ int   sm[128];
    int b = blockIdx.x, t = threadIdx.x;
    if (t < 128) { cnt[t] = 0; dsum[t] = 0.0f; cur[t] = 0; }
    __syncthreads();
    int p0 = bb[b], p1 = bb[b + 1];
    int m = p1 - p0;
    bool fits = (m <= BCAP);
    for (int p = p0 + t; p < p1; p += 256) {
        int2 v = ebuf[p];
        if (fits) stage[p - p0] = v;
        int ln = (((unsigned)v.x) >> 24) & 127;
        atomicAdd(&cnt[ln], 1);
        atomicAdd(&dsum[ln], __int_as_float(v.y));
    }
    __syncthreads();
    if (t < 128) {
        int cv = cnt[t];
        sm[t] = cv;
        __syncthreads();
        for (int off = 1; off < 128; off <<= 1) {
            int add = (t >= off) ? sm[t - off] : 0;
            __syncthreads();
            sm[t] += add;
            __syncthreads();
        }
        lrp[t] = sm[t] - cv + p0;     // absolute csw base for local node t
        int d = (b << BSH) + t;
        if (d < N) {
            rp[d]   = lrp[t];
            dinv[d] = rsqrtf(1.0f + dsum[t]);
        }
        if (b == 0 && t == 0) rp[N] = E;
    } else {
        __syncthreads();
        for (int off = 1; off < 128; off <<= 1) { __syncthreads(); __syncthreads(); }
    }
    __syncthreads();
    for (int q = t; q < m; q += 256) {
        int2 v = fits ? stage[q] : ebuf[p0 + q];
        int ln = (((unsigned)v.x) >> 24) & 127;
        int r = atomicAdd(&cur[ln], 1);   // LDS atomic
        csw[lrp[ln] + r] = make_int2(v.x & 0xFFFFFF, v.y);  // raw w
    }
}

// ---------------- K6: h1 = fp16(x @ W1)  (N x 128 @ 128 x 64) ------
__global__ __launch_bounds__(256) void k_gemm1(const float* __restrict__ x,
                                               const float* __restrict__ W1,
                                               __half* __restrict__ h1,
                                               int N, int iters) {
    __shared__ float wlds[DIN * DHID];  // 32 KB
    __shared__ float xs[4][DIN];        // 2 KB
    for (int t = threadIdx.x; t < DIN * DHID; t += 256) wlds[t] = W1[t];
    __syncthreads();
    int g = threadIdx.x >> 6;
    int lane = threadIdx.x & 63;
    for (int it = 0; it < iters; ++it) {
        int r = blockIdx.x * 4 + g + it * gridDim.x * 4;
        if (r < N) {
            xs[g][lane]      = x[r * DIN + lane];
            xs[g][lane + 64] = x[r * DIN + 64 + lane];
        }
        __syncthreads();
        if (r < N) {
            float acc = 0.0f;
#pragma unroll 8
            for (int k = 0; k < DIN; ++k)
                acc = fmaf(xs[g][k], wlds[k * DHID + lane], acc);
            h1[r * DHID + lane] = __float2half(acc);
        }
        __syncthreads();
    }
}

// ------- K7: fused layer-1 aggregate + bias + ReLU + @W2 -----------
// one wave per node; lane = feature; wave-uniform scalar edge loads,
// one coalesced 128B fp16-row gather per edge. No shuffles in the loop.
__global__ __launch_bounds__(256) void k_agg1(const __half* __restrict__ h1h,
                                              const int* __restrict__ rp,
                                              const int2* __restrict__ csw,
                                              const float* __restrict__ dinv,
                                              const float* __restrict__ b1,
                                              const float* __restrict__ W2,
                                              float* __restrict__ h2, int N) {
    int lane = threadIdx.x & 63;
    int i = (blockIdx.x * 256 + threadIdx.x) >> 6;
    if (i >= N) return;
    float bias = b1[lane];
    float w2a = W2[lane * 2];
    float w2b = W2[lane * 2 + 1];
    int s0 = __builtin_amdgcn_readfirstlane(rp[i]);
    int e0 = __builtin_amdgcn_readfirstlane(rp[i + 1]);
    float acc = 0.0f;
    int p = s0;
    for (; p + 4 <= e0; p += 4) {
        int2 eA = csw[p], eB = csw[p + 1], eC = csw[p + 2], eD = csw[p + 3];
        int sA = __builtin_amdgcn_readfirstlane(eA.x);
        int sB = __builtin_amdgcn_readfirstlane(eB.x);
        int sC = __builtin_amdgcn_readfirstlane(eC.x);
        int sD = __builtin_amdgcn_readfirstlane(eD.x);
        float wA = __uint_as_float(__builtin_amdgcn_readfirstlane(eA.y)) * dinv[sA];
        float wB = __uint_as_float(__builtin_amdgcn_readfirstlane(eB.y)) * dinv[sB];
        float wC = __uint_as_float(__builtin_amdgcn_readfirstlane(eC.y)) * dinv[sC];
        float wD = __uint_as_float(__builtin_amdgcn_readfirstlane(eD.y)) * dinv[sD];
        float hA = __half2float(h1h[sA * DHID + lane]);
        float hB = __half2float(h1h[sB * DHID + lane]);
        float hC = __half2float(h1h[sC * DHID + lane]);
        float hD = __half2float(h1h[sD * DHID + lane]);
        acc = fmaf(wA, hA, acc);
        acc = fmaf(wB, hB, acc);
        acc = fmaf(wC, hC, acc);
        acc = fmaf(wD, hD, acc);
    }
    for (; p < e0; ++p) {
        int2 eA = csw[p];
        int sA = __builtin_amdgcn_readfirstlane(eA.x);
        float wA = __uint_as_float(__builtin_amdgcn_readfirstlane(eA.y)) * dinv[sA];
        acc = fmaf(wA, __half2float(h1h[sA * DHID + lane]), acc);
    }
    // self-loop + dst-side norm: di*(edge_sum + di*self)
    float di = dinv[i];
    acc = (acc + di * __half2float(h1h[i * DHID + lane])) * di;
    acc = fmaxf(acc + bias, 0.0f);
    float o0 = acc * w2a, o1 = acc * w2b;
    for (int off = 32; off > 0; off >>= 1) {
        o0 += __shfl_xor(o0, off);
        o1 += __shfl_xor(o1, off);
    }
    if (lane == 0) {
        h2[i * 2]     = o0;
        h2[i * 2 + 1] = o1;
    }
}

// ------- K8: layer-2 propagate: out = di*(sum + di*self) + b2 ------
__global__ __launch_bounds__(256) void k_prop2(const float* __restrict__ h2,
                                               const int* __restrict__ rp,
                                               const int2* __restrict__ csw,
                                               const float* __restrict__ dinv,
                                               const float* __restrict__ b2,
                                               float* __restrict__ out, int N) {
    const float2* h2v = (const float2*)h2;
    int lane = threadIdx.x & 63;
    int i = (blockIdx.x * 256 + threadIdx.x) >> 6;
    if (i >= N) return;
    float b20 = b2[0], b21 = b2[1];
    int s0 = rp[i], e0 = rp[i + 1];
    float a0 = 0.0f, a1 = 0.0f;
    for (int p = s0 + lane; p < e0; p += 64) {
        int2 ed = csw[p];
        float w = __int_as_float(ed.y) * dinv[ed.x];  // raw w * dinv[src]
        float2 hv = h2v[ed.x];
        a0 = fmaf(w, hv.x, a0);
        a1 = fmaf(w, hv.y, a1);
    }
    for (int off = 32; off > 0; off >>= 1) {
        a0 += __shfl_xor(a0, off);
        a1 += __shfl_xor(a1, off);
    }
    if (lane == 0) {
        float di = dinv[i];
        out[i * 2]     = di * (a0 + di * h2[i * 2])     + b20;
        out[i * 2 + 1] = di * (a1 + di * h2[i * 2 + 1]) + b21;
    }
}

extern "C" void kernel_launch(void* const* d_in, const int* in_sizes, int n_in,
                              void* d_out, int out_size, void* d_ws, size_t ws_size,
                              hipStream_t stream) {
    const float* x  = (const float*)d_in[0];
    const int*   ei = (const int*)d_in[1];     // int32 per harness contract
    const float* ew = (const float*)d_in[2];
    const float* W1 = (const float*)d_in[3];
    const float* b1 = (const float*)d_in[4];
    const float* W2 = (const float*)d_in[5];
    const float* b2 = (const float*)d_in[6];
    float* out = (float*)d_out;

    const int N = in_sizes[0] / DIN;   // 100000
    const int E = in_sizes[2];         // 3200000

    const int C = 256;                 // edge chunks
    const int B = (N + 127) >> BSH;    // 782 buckets of 128 nodes
    const int chunk = (E + C - 1) / C;

    // workspace layout (~53 MB; ebuf aliased by h1/h2 after k_build)
    char* w0 = (char*)d_ws;
    float* dinv  = (float*)w0;                      // N floats
    int*   rp    = (int*)(dinv + N);                // N+1 ints (+3 pad)
    int*   histT = rp + (N + 4);                    // B*C ints (800 KB)
    int*   tot   = histT + (size_t)B * C;           // B ints
    int*   bb    = tot + B;                         // B+1 ints
    size_t off_csw = ((size_t)((char*)(bb + B + 1) - w0) + 15) & ~(size_t)15;
    int2*  csw  = (int2*)(w0 + off_csw);            // E pairs (25.6 MB)
    int2*  ebuf = csw + E;                          // E pairs (25.6 MB)
    __half* h1  = (__half*)ebuf;                    // alias: N*64 fp16 (12.8 MB)
    float* h2   = (float*)(h1 + (size_t)N * DHID);  // alias: N*2 fp32

    size_t ldsB = (size_t)B * sizeof(int);

    k_hist<<<C, 256, ldsB, stream>>>(ei, histT, E, chunk, B, C);
    k_scan1<<<B, 256, 0, stream>>>(histT, tot, C);
    k_scan2<<<1, 1024, 0, stream>>>(tot, bb, B);
    k_scatter<<<C, 256, ldsB, stream>>>(ei, ew, histT, bb, ebuf, E, chunk, B, C);
    k_build<<<B, 256, 0, stream>>>(ebuf, bb, rp, dinv, csw, N, E);

    const int G8 = 1024;
    const int iters = (N + G8 * 4 - 1) / (G8 * 4);
    k_gemm1<<<G8, 256, 0, stream>>>(x, W1, h1, N, iters);

    const int GW = ((size_t)N * 64 + 255) / 256;   // one wave per node
    k_agg1<<<GW, 256, 0, stream>>>(h1, rp, csw, dinv, b1, W2, h2, N);
    k_prop2<<<GW, 256, 0, stream>>>(h2, rp, csw, dinv, b2, out, N);
}

// Round 9
// 403.450 us; speedup vs baseline: 2.2397x; 1.1425x over previous
//
#include <hip/hip_runtime.h>
#include <hip/hip_bf16.h>
#include <hip/hip_fp16.h>

// 2-layer GCN, N=100000 nodes, E=3.2M edges, dims 128 -> 64 -> 2, fp32.
// R9: k_gemm1 was LDS-issue-bound (~2 ds_read per fma, est ~150us hidden in
// the profile tail). Rewritten with mfma_f32_16x16x32_f16: 64-row blocks,
// fp16 x-tile + fp16 W1 in padded LDS, 16 MFMAs/wave. W1 pre-converted to
// fp16 once (k_w1h). Everything else unchanged from R8.

#define DIN  128
#define DHID 64
#define BSH  7                    // bucket shift: 128 nodes/bucket
#define BCAP 5000                 // LDS staging capacity (edges/bucket)

typedef _Float16 half8 __attribute__((ext_vector_type(8)));
typedef float    f32x4 __attribute__((ext_vector_type(4)));

// ---------------- K1: per-chunk coarse histogram (LDS only) --------
__global__ __launch_bounds__(256) void k_hist(const int* __restrict__ ei,
                                              int* __restrict__ histT,
                                              int E, int chunk, int B, int C) {
    extern __shared__ int h[];
    for (int t = threadIdx.x; t < B; t += 256) h[t] = 0;
    __syncthreads();
    int c = blockIdx.x;
    int e0 = c * chunk, e1 = min(E, e0 + chunk);
    for (int e = e0 + threadIdx.x; e < e1; e += 256)
        atomicAdd(&h[ei[E + e] >> BSH], 1);
    __syncthreads();
    for (int t = threadIdx.x; t < B; t += 256) histT[(size_t)t * C + c] = h[t];
}

// ------- K2: per-bucket exclusive scan over its 256 chunk-cells ----
__global__ __launch_bounds__(256) void k_scan1(int* __restrict__ histT,
                                               int* __restrict__ tot, int C) {
    __shared__ int sm[256];
    int b = blockIdx.x, t = threadIdx.x;
    size_t base = (size_t)b * C;
    int v = histT[base + t];
    sm[t] = v;
    __syncthreads();
    for (int off = 1; off < 256; off <<= 1) {
        int add = (t >= off) ? sm[t - off] : 0;
        __syncthreads();
        sm[t] += add;
        __syncthreads();
    }
    histT[base + t] = sm[t] - v;          // exclusive within bucket
    if (t == 255) tot[b] = sm[t];
}

// ------- K3: exclusive scan of bucket totals -> bucket bases -------
__global__ __launch_bounds__(1024) void k_scan2(const int* __restrict__ tot,
                                                int* __restrict__ bb, int B) {
    __shared__ int sm[1024];
    int t = threadIdx.x;
    int v = (t < B) ? tot[t] : 0;
    sm[t] = v;
    __syncthreads();
    for (int off = 1; off < 1024; off <<= 1) {
        int add = (t >= off) ? sm[t - off] : 0;
        __syncthreads();
        sm[t] += add;
        __syncthreads();
    }
    if (t < B) {
        bb[t] = sm[t] - v;
        if (t == B - 1) bb[B] = sm[t];
    }
}

// ---------------- K4: scatter edges into bucket-sorted ebuf --------
__global__ __launch_bounds__(256) void k_scatter(const int* __restrict__ ei,
                                                 const float* __restrict__ ew,
                                                 const int* __restrict__ histT,
                                                 const int* __restrict__ bb,
                                                 int2* __restrict__ ebuf,
                                                 int E, int chunk, int B, int C) {
    extern __shared__ int cur[];
    int c = blockIdx.x;
    for (int t = threadIdx.x; t < B; t += 256)
        cur[t] = histT[(size_t)t * C + c] + bb[t];
    __syncthreads();
    int e0 = c * chunk, e1 = min(E, e0 + chunk);
    for (int e = e0 + threadIdx.x; e < e1; e += 256) {
        int s = ei[e];
        int d = ei[E + e];
        float w = ew[e];
        int b = d >> BSH;
        int pos = atomicAdd(&cur[b], 1);   // LDS atomic
        ebuf[pos] = make_int2(s | ((d & 127) << 24), __float_as_int(w));
    }
}

// ---------------- K5: per-bucket CSR build (rp, dinv, csw) ---------
__global__ __launch_bounds__(256) void k_build(const int2* __restrict__ ebuf,
                                               const int* __restrict__ bb,
                                               int* __restrict__ rp,
                                               float* __restrict__ dinv,
                                               int2* __restrict__ csw,
                                               int N, int E) {
    __shared__ int2  stage[BCAP];   // 40 KB
    __shared__ int   cnt[128];
    __shared__ float dsum[128];
    __shared__ int   lrp[128];
    __shared__ int   cur[128];
    __shared__ int   sm[128];
    int b = blockIdx.x, t = threadIdx.x;
    if (t < 128) { cnt[t] = 0; dsum[t] = 0.0f; cur[t] = 0; }
    __syncthreads();
    int p0 = bb[b], p1 = bb[b + 1];
    int m = p1 - p0;
    bool fits = (m <= BCAP);
    for (int p = p0 + t; p < p1; p += 256) {
        int2 v = ebuf[p];
        if (fits) stage[p - p0] = v;
        int ln = (((unsigned)v.x) >> 24) & 127;
        atomicAdd(&cnt[ln], 1);
        atomicAdd(&dsum[ln], __int_as_float(v.y));
    }
    __syncthreads();
    if (t < 128) {
        int cv = cnt[t];
        sm[t] = cv;
        __syncthreads();
        for (int off = 1; off < 128; off <<= 1) {
            int add = (t >= off) ? sm[t - off] : 0;
            __syncthreads();
            sm[t] += add;
            __syncthreads();
        }
        lrp[t] = sm[t] - cv + p0;     // absolute csw base for local node t
        int d = (b << BSH) + t;
        if (d < N) {
            rp[d]   = lrp[t];
            dinv[d] = rsqrtf(1.0f + dsum[t]);
        }
        if (b == 0 && t == 0) rp[N] = E;
    } else {
        __syncthreads();
        for (int off = 1; off < 128; off <<= 1) { __syncthreads(); __syncthreads(); }
    }
    __syncthreads();
    for (int q = t; q < m; q += 256) {
        int2 v = fits ? stage[q] : ebuf[p0 + q];
        int ln = (((unsigned)v.x) >> 24) & 127;
        int r = atomicAdd(&cur[ln], 1);   // LDS atomic
        csw[lrp[ln] + r] = make_int2(v.x & 0xFFFFFF, v.y);  // raw w
    }
}

// ---------------- K6a: W1 -> fp16 (one block) ----------------------
__global__ __launch_bounds__(256) void k_w1h(const float* __restrict__ W1,
                                             __half* __restrict__ W1h) {
    for (int i = threadIdx.x; i < DIN * DHID; i += 256)
        W1h[i] = __float2half(W1[i]);
}

// ---------------- K6b: h1 = fp16(x @ W1) via MFMA ------------------
// 64 rows/block; 4 waves, wave w -> rows [w*16, w*16+16) x all 64 cols.
// A (x-tile) and B (W1, col-major) in LDS, padded to 136 fp16/row.
__global__ __launch_bounds__(256) void k_gemm1(const float* __restrict__ x,
                                               const __half* __restrict__ W1h,
                                               __half* __restrict__ h1, int N) {
    __shared__ _Float16 As[64][136];   // 17 KB (pad 8 -> 2-way bank alias)
    __shared__ _Float16 Bs[64][136];   // Bs[col][k]
    int t = threadIdx.x;
    int wave = t >> 6, lane = t & 63;
    int r0 = blockIdx.x * 64;

    // B: W1h row-major [k][c] -> LDS col-major Bs[c][k]
    for (int idx = t; idx < DIN * DHID; idx += 256) {
        int k = idx >> 6, c = idx & 63;
        Bs[c][k] = (_Float16)__half2float(W1h[idx]);
    }
    // A: x rows r0..r0+63 (fp32, float4 coalesced) -> fp16 LDS
    const float4* xv = (const float4*)x;
    for (int idx = t; idx < 64 * 32; idx += 256) {
        int r = idx >> 5, c4 = idx & 31;
        int rr = r0 + r;
        float4 v = (rr < N) ? xv[(size_t)rr * 32 + c4]
                            : make_float4(0.f, 0.f, 0.f, 0.f);
        As[r][c4 * 4 + 0] = (_Float16)v.x;
        As[r][c4 * 4 + 1] = (_Float16)v.y;
        As[r][c4 * 4 + 2] = (_Float16)v.z;
        As[r][c4 * 4 + 3] = (_Float16)v.w;
    }
    __syncthreads();

    int row = lane & 15;
    int kg  = lane >> 4;               // k-subgroup 0..3 (8 k each)
    f32x4 acc0 = {0.f,0.f,0.f,0.f}, acc1 = {0.f,0.f,0.f,0.f};
    f32x4 acc2 = {0.f,0.f,0.f,0.f}, acc3 = {0.f,0.f,0.f,0.f};
#pragma unroll
    for (int kc = 0; kc < 4; ++kc) {
        half8 a = *(const half8*)&As[wave * 16 + row][kc * 32 + kg * 8];
        half8 b0 = *(const half8*)&Bs[ 0 + row][kc * 32 + kg * 8];
        half8 b1 = *(const half8*)&Bs[16 + row][kc * 32 + kg * 8];
        half8 b2 = *(const half8*)&Bs[32 + row][kc * 32 + kg * 8];
        half8 b3 = *(const half8*)&Bs[48 + row][kc * 32 + kg * 8];
        acc0 = __builtin_amdgcn_mfma_f32_16x16x32_f16(a, b0, acc0, 0, 0, 0);
        acc1 = __builtin_amdgcn_mfma_f32_16x16x32_f16(a, b1, acc1, 0, 0, 0);
        acc2 = __builtin_amdgcn_mfma_f32_16x16x32_f16(a, b2, acc2, 0, 0, 0);
        acc3 = __builtin_amdgcn_mfma_f32_16x16x32_f16(a, b3, acc3, 0, 0, 0);
    }
    // C/D: col = lane&15, row = (lane>>4)*4 + reg  (m89-verified)
#pragma unroll
    for (int reg = 0; reg < 4; ++reg) {
        int rr = r0 + wave * 16 + kg * 4 + reg;
        if (rr < N) {
            int col = lane & 15;
            size_t base = (size_t)rr * DHID;
            h1[base + col +  0] = __float2half(acc0[reg]);
            h1[base + col + 16] = __float2half(acc1[reg]);
            h1[base + col + 32] = __float2half(acc2[reg]);
            h1[base + col + 48] = __float2half(acc3[reg]);
        }
    }
}

// ------- K7: fused layer-1 aggregate + bias + ReLU + @W2 -----------
// one wave per node; lane = feature; wave-uniform scalar edge loads,
// one coalesced 128B fp16-row gather per edge.
__global__ __launch_bounds__(256) void k_agg1(const __half* __restrict__ h1h,
                                              const int* __restrict__ rp,
                                              const int2* __restrict__ csw,
                                              const float* __restrict__ dinv,
                                              const float* __restrict__ b1,
                                              const float* __restrict__ W2,
                                              float* __restrict__ h2, int N) {
    int lane = threadIdx.x & 63;
    int i = (blockIdx.x * 256 + threadIdx.x) >> 6;
    if (i >= N) return;
    float bias = b1[lane];
    float w2a = W2[lane * 2];
    float w2b = W2[lane * 2 + 1];
    int s0 = __builtin_amdgcn_readfirstlane(rp[i]);
    int e0 = __builtin_amdgcn_readfirstlane(rp[i + 1]);
    float acc = 0.0f;
    int p = s0;
    for (; p + 4 <= e0; p += 4) {
        int2 eA = csw[p], eB = csw[p + 1], eC = csw[p + 2], eD = csw[p + 3];
        int sA = __builtin_amdgcn_readfirstlane(eA.x);
        int sB = __builtin_amdgcn_readfirstlane(eB.x);
        int sC = __builtin_amdgcn_readfirstlane(eC.x);
        int sD = __builtin_amdgcn_readfirstlane(eD.x);
        float wA = __uint_as_float(__builtin_amdgcn_readfirstlane(eA.y)) * dinv[sA];
        float wB = __uint_as_float(__builtin_amdgcn_readfirstlane(eB.y)) * dinv[sB];
        float wC = __uint_as_float(__builtin_amdgcn_readfirstlane(eC.y)) * dinv[sC];
        float wD = __uint_as_float(__builtin_amdgcn_readfirstlane(eD.y)) * dinv[sD];
        float hA = __half2float(h1h[sA * DHID + lane]);
        float hB = __half2float(h1h[sB * DHID + lane]);
        float hC = __half2float(h1h[sC * DHID + lane]);
        float hD = __half2float(h1h[sD * DHID + lane]);
        acc = fmaf(wA, hA, acc);
        acc = fmaf(wB, hB, acc);
        acc = fmaf(wC, hC, acc);
        acc = fmaf(wD, hD, acc);
    }
    for (; p < e0; ++p) {
        int2 eA = csw[p];
        int sA = __builtin_amdgcn_readfirstlane(eA.x);
        float wA = __uint_as_float(__builtin_amdgcn_readfirstlane(eA.y)) * dinv[sA];
        acc = fmaf(wA, __half2float(h1h[sA * DHID + lane]), acc);
    }
    // self-loop + dst-side norm: di*(edge_sum + di*self)
    float di = dinv[i];
    acc = (acc + di * __half2float(h1h[i * DHID + lane])) * di;
    acc = fmaxf(acc + bias, 0.0f);
    float o0 = acc * w2a, o1 = acc * w2b;
    for (int off = 32; off > 0; off >>= 1) {
        o0 += __shfl_xor(o0, off);
        o1 += __shfl_xor(o1, off);
    }
    if (lane == 0) {
        h2[i * 2]     = o0;
        h2[i * 2 + 1] = o1;
    }
}

// ------- K8: layer-2 propagate: out = di*(sum + di*self) + b2 ------
__global__ __launch_bounds__(256) void k_prop2(const float* __restrict__ h2,
                                               const int* __restrict__ rp,
                                               const int2* __restrict__ csw,
                                               const float* __restrict__ dinv,
                                               const float* __restrict__ b2,
                                               float* __restrict__ out, int N) {
    const float2* h2v = (const float2*)h2;
    int lane = threadIdx.x & 63;
    int i = (blockIdx.x * 256 + threadIdx.x) >> 6;
    if (i >= N) return;
    float b20 = b2[0], b21 = b2[1];
    int s0 = rp[i], e0 = rp[i + 1];
    float a0 = 0.0f, a1 = 0.0f;
    for (int p = s0 + lane; p < e0; p += 64) {
        int2 ed = csw[p];
        float w = __int_as_float(ed.y) * dinv[ed.x];  // raw w * dinv[src]
        float2 hv = h2v[ed.x];
        a0 = fmaf(w, hv.x, a0);
        a1 = fmaf(w, hv.y, a1);
    }
    for (int off = 32; off > 0; off >>= 1) {
        a0 += __shfl_xor(a0, off);
        a1 += __shfl_xor(a1, off);
    }
    if (lane == 0) {
        float di = dinv[i];
        out[i * 2]     = di * (a0 + di * h2[i * 2])     + b20;
        out[i * 2 + 1] = di * (a1 + di * h2[i * 2 + 1]) + b21;
    }
}

extern "C" void kernel_launch(void* const* d_in, const int* in_sizes, int n_in,
                              void* d_out, int out_size, void* d_ws, size_t ws_size,
                              hipStream_t stream) {
    const float* x  = (const float*)d_in[0];
    const int*   ei = (const int*)d_in[1];     // int32 per harness contract
    const float* ew = (const float*)d_in[2];
    const float* W1 = (const float*)d_in[3];
    const float* b1 = (const float*)d_in[4];
    const float* W2 = (const float*)d_in[5];
    const float* b2 = (const float*)d_in[6];
    float* out = (float*)d_out;

    const int N = in_sizes[0] / DIN;   // 100000
    const int E = in_sizes[2];         // 3200000

    const int C = 256;                 // edge chunks
    const int B = (N + 127) >> BSH;    // 782 buckets of 128 nodes
    const int chunk = (E + C - 1) / C;

    // workspace layout (~53 MB; ebuf aliased by h1/h2/W1h after k_build)
    char* w0 = (char*)d_ws;
    float* dinv  = (float*)w0;                      // N floats
    int*   rp    = (int*)(dinv + N);                // N+1 ints (+3 pad)
    int*   histT = rp + (N + 4);                    // B*C ints (800 KB)
    int*   tot   = histT + (size_t)B * C;           // B ints
    int*   bb    = tot + B;                         // B+1 ints
    size_t off_csw = ((size_t)((char*)(bb + B + 1) - w0) + 15) & ~(size_t)15;
    int2*  csw  = (int2*)(w0 + off_csw);            // E pairs (25.6 MB)
    int2*  ebuf = csw + E;                          // E pairs (25.6 MB)
    __half* h1  = (__half*)ebuf;                    // alias: N*64 fp16 (12.8 MB)
    float* h2   = (float*)(h1 + (size_t)N * DHID);  // alias: N*2 fp32
    __half* W1h = (__half*)(h2 + 2 * N);            // alias: 8192 fp16 (16 KB)

    size_t ldsB = (size_t)B * sizeof(int);

    k_hist<<<C, 256, ldsB, stream>>>(ei, histT, E, chunk, B, C);
    k_scan1<<<B, 256, 0, stream>>>(histT, tot, C);
    k_scan2<<<1, 1024, 0, stream>>>(tot, bb, B);
    k_scatter<<<C, 256, ldsB, stream>>>(ei, ew, histT, bb, ebuf, E, chunk, B, C);
    k_build<<<B, 256, 0, stream>>>(ebuf, bb, rp, dinv, csw, N, E);

    k_w1h<<<1, 256, 0, stream>>>(W1, W1h);          // after k_build (alias!)
    const int GB = (N + 63) / 64;
    k_gemm1<<<GB, 256, 0, stream>>>(x, W1h, h1, N);

    const int GW = ((size_t)N * 64 + 255) / 256;   // one wave per node
    k_agg1<<<GW, 256, 0, stream>>>(h1, rp, csw, dinv, b1, W2, h2, N);
    k_prop2<<<GW, 256, 0, stream>>>(h2, rp, csw, dinv, b2, out, N);
}